// Round 1
// baseline (427.247 us; speedup 1.0000x reference)
//
#include <hip/hip_runtime.h>
#include <cstdint>

typedef unsigned short ushort_t;
typedef __attribute__((ext_vector_type(8))) short bf16x8;
typedef __attribute__((ext_vector_type(4))) float f32x4;

#define S_LEN 1024
#define DHEAD 64

// fp32 -> bf16 round-to-nearest-even
__device__ inline ushort_t f2bf(float f) {
    union { float f; uint32_t u; } c; c.f = f;
    uint32_t u = c.u;
    uint32_t r = u + 0x7FFFu + ((u >> 16) & 1u);
    return (ushort_t)(r >> 16);
}
__device__ inline float bf2f(ushort_t h) {
    union { uint32_t u; float f; } c; c.u = ((uint32_t)h) << 16;
    return c.f;
}
__device__ inline bf16x8 load8(const ushort_t* p) {
    union { uint4 u; bf16x8 v; } c;
    c.u = *reinterpret_cast<const uint4*>(p);
    return c.v;
}

// ---------------------------------------------------------------------------
// prep: convert 4 activations fp32->bf16; transpose+convert 5 weights (512x512)
// ws layout (ushort elements):
//   qb=0, kb=4M, vb=8M, pb=12M, wT=16M (5 x 262144), Qu=18874368, Qv=23068672,
//   Kp=27262976 ; aliases after producers die: Pp=qb, Vt=kb, ctx=vb
// ---------------------------------------------------------------------------
__global__ void prep_kernel(const float* __restrict__ q, const float* __restrict__ k,
                            const float* __restrict__ v, const float* __restrict__ p,
                            const float* __restrict__ wq, const float* __restrict__ wk,
                            const float* __restrict__ wv, const float* __restrict__ wp,
                            const float* __restrict__ wo,
                            ushort_t* __restrict__ ws) {
    int t = blockIdx.x * 256 + threadIdx.x;   // 0..1048575
    int sec = blockIdx.y;
    if (sec < 4) {
        const float* src = sec == 0 ? q : sec == 1 ? k : sec == 2 ? v : p;
        ushort_t* dst = ws + (size_t)sec * 4194304;
        float4 f = reinterpret_cast<const float4*>(src)[t];
        ushort4 o;
        o.x = f2bf(f.x); o.y = f2bf(f.y); o.z = f2bf(f.z); o.w = f2bf(f.w);
        *reinterpret_cast<ushort4*>(dst + (size_t)t * 4) = o;
    } else {
        int wi = sec - 4;
        if (t < 262144) {
            const float* src = wi == 0 ? wq : wi == 1 ? wk : wi == 2 ? wv : wi == 3 ? wp : wo;
            int r = t >> 9, c = t & 511;
            // store W^T: row = output col, col = k
            ws[16777216 + (size_t)wi * 262144 + (size_t)c * 512 + r] = f2bf(src[t]);
        }
    }
}

// ---------------------------------------------------------------------------
// bf16 MFMA GEMM: out[8192x512] = A[8192x512] @ Bt^T + bias
// MODE 0: write Qu=acc+bias+u, Qv=acc+bias+v scattered to [bh][s][dh]
// MODE 1: write out1 scattered to [bh][s][dh] (bias may be null -> P proj)
// MODE 2: write out1 scattered transposed [bh][dh][s] (V for PV B-operand)
// MODE 3: write fp32 straight [row][col] + bias (final output)
// ---------------------------------------------------------------------------
template<int MODE>
__global__ __launch_bounds__(256) void gemm_kernel(
    const ushort_t* __restrict__ A, const ushort_t* __restrict__ Bt,
    const float* __restrict__ bias, const float* __restrict__ add_u,
    const float* __restrict__ add_v,
    ushort_t* __restrict__ out1, ushort_t* __restrict__ out2,
    float* __restrict__ outf) {
    __shared__ ushort_t As[128][72];   // pad 64->72 keeps 16B align, spreads banks
    __shared__ ushort_t Bs[128][72];
    int tid = threadIdx.x;
    int wid = tid >> 6, lane = tid & 63, quad = lane >> 4, l16 = lane & 15;
    int wr = wid >> 1, wc = wid & 1;
    int row0 = blockIdx.y * 128, col0 = blockIdx.x * 128;

    f32x4 acc[4][4];
#pragma unroll
    for (int i = 0; i < 4; i++)
#pragma unroll
        for (int j = 0; j < 4; j++) acc[i][j] = (f32x4){0.f, 0.f, 0.f, 0.f};

    for (int k0 = 0; k0 < 512; k0 += 64) {
#pragma unroll
        for (int i = 0; i < 4; i++) {
            int cid = tid + i * 256;
            int r = cid >> 3, c8 = cid & 7;
            *reinterpret_cast<uint4*>(&As[r][c8 * 8]) =
                *reinterpret_cast<const uint4*>(A + (size_t)(row0 + r) * 512 + k0 + c8 * 8);
            *reinterpret_cast<uint4*>(&Bs[r][c8 * 8]) =
                *reinterpret_cast<const uint4*>(Bt + (size_t)(col0 + r) * 512 + k0 + c8 * 8);
        }
        __syncthreads();
#pragma unroll
        for (int kc = 0; kc < 2; kc++) {
            bf16x8 af[4], bg[4];
#pragma unroll
            for (int m = 0; m < 4; m++)
                af[m] = load8(&As[wr * 64 + m * 16 + l16][kc * 32 + quad * 8]);
#pragma unroll
            for (int n = 0; n < 4; n++)
                bg[n] = load8(&Bs[wc * 64 + n * 16 + l16][kc * 32 + quad * 8]);
#pragma unroll
            for (int m = 0; m < 4; m++)
#pragma unroll
                for (int n = 0; n < 4; n++)
                    acc[m][n] = __builtin_amdgcn_mfma_f32_16x16x32_bf16(af[m], bg[n], acc[m][n], 0, 0, 0);
        }
        __syncthreads();
    }

#pragma unroll
    for (int m = 0; m < 4; m++) {
#pragma unroll
        for (int n = 0; n < 4; n++) {
            int col = col0 + wc * 64 + n * 16 + l16;
#pragma unroll
            for (int r = 0; r < 4; r++) {
                int row = row0 + wr * 64 + m * 16 + quad * 4 + r;  // C/D: row=(lane>>4)*4+reg
                float val = acc[m][n][r];
                if (MODE == 3) {
                    outf[(size_t)row * 512 + col] = val + bias[col];
                } else {
                    if (bias) val += bias[col];
                    int b_ = row >> 10, s_ = row & 1023, h_ = col >> 6, d_ = col & 63;
                    if (MODE == 0) {
                        size_t idx = (((size_t)(b_ * 8 + h_)) * 1024 + s_) * 64 + d_;
                        out1[idx] = f2bf(val + add_u[col]);   // u_bias flat == col index
                        out2[idx] = f2bf(val + add_v[col]);
                    } else if (MODE == 1) {
                        size_t idx = (((size_t)(b_ * 8 + h_)) * 1024 + s_) * 64 + d_;
                        out1[idx] = f2bf(val);
                    } else {  // MODE 2: V transposed [bh][dh][s]
                        size_t idx = (((size_t)(b_ * 8 + h_)) * 64 + d_) * 1024 + s_;
                        out1[idx] = f2bf(val);
                    }
                }
            }
        }
    }
}

// ---------------------------------------------------------------------------
// Fused attention: block = (bh, 16 query rows). 4 waves, wave w owns k-range
// [w*256,(w+1)*256). Content scores via MFMA; pos via rel-shift closed form:
//   shift[q,k] = F[q][S-1-q+k] (k<=q) ; 0 (k=q+1) ; F[q+1][k-q-2] (k>=q+2)
// computed as two sliding-window MFMA passes with scatter-add into LDS scores.
// Then full-row softmax, then PV MFMA (wave w owns d-cols [w*16,(w+1)*16)).
// ---------------------------------------------------------------------------
__global__ __launch_bounds__(256) void attn_kernel(
    const ushort_t* __restrict__ Qu, const ushort_t* __restrict__ Qv,
    const ushort_t* __restrict__ Kp, const ushort_t* __restrict__ Pp,
    const ushort_t* __restrict__ Vt, ushort_t* __restrict__ ctxb) {
    __shared__ ushort_t sc[16][1032];   // bf16 raw scores, pad 1024->1032
    __shared__ float red[16][16];
    __shared__ float rowmax_s[16];
    __shared__ float rowinv_s[16];

    constexpr float SCL = (float)(1.4426950408889634 / 22.627416997969522); // log2(e)/sqrt(512)

    int bx = blockIdx.x;
    int bh = bx >> 6, qt = bx & 63, q0 = qt << 4;
    int tid = threadIdx.x, wid = tid >> 6, lane = tid & 63;
    int quad = lane >> 4, l16 = lane & 15;

    const ushort_t* Qu_b = Qu + (size_t)bh * S_LEN * DHEAD;
    const ushort_t* Qv_b = Qv + (size_t)bh * S_LEN * DHEAD;
    const ushort_t* K_b  = Kp + (size_t)bh * S_LEN * DHEAD;
    const ushort_t* P_b  = Pp + (size_t)bh * S_LEN * DHEAD;
    const ushort_t* V_b  = Vt + (size_t)bh * DHEAD * S_LEN;

    // A-operand frags: A[m=lane&15][k=quad*8+j]
    bf16x8 au[2], av1[2], av2[2];
#pragma unroll
    for (int kc = 0; kc < 2; kc++) {
        au[kc]  = load8(Qu_b + (size_t)(q0 + l16) * 64 + kc * 32 + quad * 8);
        av1[kc] = load8(Qv_b + (size_t)(q0 + l16) * 64 + kc * 32 + quad * 8);
        int r2 = q0 + 1 + l16; if (r2 > S_LEN - 1) r2 = S_LEN - 1;  // clamped row unused (guarded)
        av2[kc] = load8(Qv_b + (size_t)r2 * 64 + kc * 32 + quad * 8);
    }

    int kw0 = wid << 8, kw1 = kw0 + 256;

    // ---- content scores ----
    for (int nt = 0; nt < 16; ++nt) {
        int kt = kw0 + nt * 16;
        bf16x8 b0 = load8(K_b + (size_t)(kt + l16) * 64 + quad * 8);
        bf16x8 b1 = load8(K_b + (size_t)(kt + l16) * 64 + 32 + quad * 8);
        f32x4 acc = (f32x4){0.f, 0.f, 0.f, 0.f};
        acc = __builtin_amdgcn_mfma_f32_16x16x32_bf16(au[0], b0, acc, 0, 0, 0);
        acc = __builtin_amdgcn_mfma_f32_16x16x32_bf16(au[1], b1, acc, 0, 0, 0);
#pragma unroll
        for (int r = 0; r < 4; r++) sc[quad * 4 + r][kt + l16] = f2bf(acc[r]);
    }

    // ---- pos branch 1: k <= q, col = S-1-q+k, rows q0..q0+15 ----
    if (kw0 <= q0 + 15) {
        int wlo = (S_LEN - 16) - q0 + kw0;
        int d1 = kw1 - 1 - q0; if (d1 > 0) d1 = 0;
        int whi = (S_LEN - 1) + d1;
        for (int wt = wlo; wt <= whi; wt += 16) {
            int prow = wt + l16; if (prow > S_LEN - 1) prow = S_LEN - 1;
            bf16x8 b0 = load8(P_b + (size_t)prow * 64 + quad * 8);
            bf16x8 b1 = load8(P_b + (size_t)prow * 64 + 32 + quad * 8);
            f32x4 acc = (f32x4){0.f, 0.f, 0.f, 0.f};
            acc = __builtin_amdgcn_mfma_f32_16x16x32_bf16(av1[0], b0, acc, 0, 0, 0);
            acc = __builtin_amdgcn_mfma_f32_16x16x32_bf16(av1[1], b1, acc, 0, 0, 0);
#pragma unroll
            for (int r = 0; r < 4; r++) {
                int m = quad * 4 + r, q = q0 + m;
                int wcol = wt + l16;
                int k = wcol - (S_LEN - 1) + q;
                if (k >= kw0 && k < kw1 && k <= q)
                    sc[m][k] = f2bf(bf2f(sc[m][k]) + acc[r]);
            }
        }
    }
    // ---- pos branch 2: k >= q+2, col = k-q-2, rows q0+1..q0+16 ----
    if (kw1 - 1 >= q0 + 2) {
        int wlo2 = kw0 - q0 - 17; if (wlo2 < 0) wlo2 = 0;
        int whi2 = kw1 - 3 - q0;
        for (int wt = wlo2; wt <= whi2; wt += 16) {
            int prow = wt + l16; if (prow > S_LEN - 1) prow = S_LEN - 1;
            bf16x8 b0 = load8(P_b + (size_t)prow * 64 + quad * 8);
            bf16x8 b1 = load8(P_b + (size_t)prow * 64 + 32 + quad * 8);
            f32x4 acc = (f32x4){0.f, 0.f, 0.f, 0.f};
            acc = __builtin_amdgcn_mfma_f32_16x16x32_bf16(av2[0], b0, acc, 0, 0, 0);
            acc = __builtin_amdgcn_mfma_f32_16x16x32_bf16(av2[1], b1, acc, 0, 0, 0);
#pragma unroll
            for (int r = 0; r < 4; r++) {
                int m = quad * 4 + r, q = q0 + m;
                int wcol = wt + l16;
                int k = wcol + q + 2;
                if (k >= kw0 && k < kw1)
                    sc[m][k] = f2bf(bf2f(sc[m][k]) + acc[r]);
            }
        }
    }
    __syncthreads();

    // ---- softmax over 1024 keys per row (16 threads/row) ----
    int srow = tid >> 4, sl = tid & 15;
    float mx = -1e30f;
    for (int k2 = sl; k2 < 1024; k2 += 16) mx = fmaxf(mx, bf2f(sc[srow][k2]));
    red[srow][sl] = mx;
    __syncthreads();
    if (tid < 16) {
        float m2 = red[tid][0];
        for (int j = 1; j < 16; j++) m2 = fmaxf(m2, red[tid][j]);
        rowmax_s[tid] = m2;
    }
    __syncthreads();
    float rm = rowmax_s[srow];
    float ssum = 0.f;
    for (int k2 = sl; k2 < 1024; k2 += 16) {
        float e = exp2f((bf2f(sc[srow][k2]) - rm) * SCL);
        sc[srow][k2] = f2bf(e);
        ssum += e;
    }
    red[srow][sl] = ssum;
    __syncthreads();
    if (tid < 16) {
        float s2 = 0.f;
        for (int j = 0; j < 16; j++) s2 += red[tid][j];
        rowinv_s[tid] = 1.0f / s2;
    }
    __syncthreads();

    // ---- PV: wave w computes d-cols [w*16, w*16+16), K=1024 ----
    int d0 = wid << 4;
    f32x4 acc = (f32x4){0.f, 0.f, 0.f, 0.f};
    for (int kc = 0; kc < 32; ++kc) {
        bf16x8 a = load8(&sc[l16][kc * 32 + quad * 8]);
        bf16x8 b = load8(V_b + (size_t)(d0 + l16) * 1024 + kc * 32 + quad * 8);
        acc = __builtin_amdgcn_mfma_f32_16x16x32_bf16(a, b, acc, 0, 0, 0);
    }
    int b_ = bh >> 3, h_ = bh & 7;
#pragma unroll
    for (int r = 0; r < 4; r++) {
        int m = quad * 4 + r, q = q0 + m;
        float val = acc[r] * rowinv_s[m];
        ctxb[((size_t)b_ * 1024 + q) * 512 + h_ * 64 + d0 + l16] = f2bf(val);
    }
}

extern "C" void kernel_launch(void* const* d_in, const int* in_sizes, int n_in,
                              void* d_out, int out_size, void* d_ws, size_t ws_size,
                              hipStream_t stream) {
    const float* q  = (const float*)d_in[0];
    const float* k  = (const float*)d_in[1];
    const float* v  = (const float*)d_in[2];
    const float* pe = (const float*)d_in[3];
    const float* Wq = (const float*)d_in[4];
    const float* bq = (const float*)d_in[5];
    const float* Wk = (const float*)d_in[6];
    const float* bk = (const float*)d_in[7];
    const float* Wv = (const float*)d_in[8];
    const float* bv = (const float*)d_in[9];
    const float* Wp = (const float*)d_in[10];
    const float* ub = (const float*)d_in[11];
    const float* vbias = (const float*)d_in[12];
    const float* Wo = (const float*)d_in[13];
    const float* bo = (const float*)d_in[14];
    float* out = (float*)d_out;
    ushort_t* ws = (ushort_t*)d_ws;

    // ws map (ushort elems); needs ~63 MB total
    ushort_t* qb = ws;
    ushort_t* kb = ws + 4194304;
    ushort_t* vbuf = ws + 2 * 4194304;
    ushort_t* pb = ws + 3 * 4194304;
    ushort_t* wT = ws + 4 * 4194304;            // 5 x 262144
    ushort_t* Qu = ws + 18874368;
    ushort_t* Qv = ws + 23068672;
    ushort_t* Kp = ws + 27262976;
    ushort_t* Pp = qb;     // alias: qb dead after Q-proj
    ushort_t* Vt = kb;     // alias: kb dead after K-proj
    ushort_t* ctx = vbuf;  // alias: vbuf dead after V-proj

    prep_kernel<<<dim3(4096, 9), 256, 0, stream>>>(q, k, v, pe, Wq, Wk, Wv, Wp, Wo, ws);
    gemm_kernel<0><<<dim3(4, 64), 256, 0, stream>>>(qb, wT, bq, ub, vbias, Qu, Qv, nullptr);
    gemm_kernel<1><<<dim3(4, 64), 256, 0, stream>>>(kb, wT + 262144, bk, nullptr, nullptr, Kp, nullptr, nullptr);
    gemm_kernel<1><<<dim3(4, 64), 256, 0, stream>>>(pb, wT + 3 * 262144, nullptr, nullptr, nullptr, Pp, nullptr, nullptr);
    gemm_kernel<2><<<dim3(4, 64), 256, 0, stream>>>(vbuf, wT + 2 * 262144, bv, nullptr, nullptr, Vt, nullptr, nullptr);
    attn_kernel<<<4096, 256, 0, stream>>>(Qu, Qv, Kp, Pp, Vt, ctx);
    gemm_kernel<3><<<dim3(4, 64), 256, 0, stream>>>(ctx, wT + 4 * 262144, bo, nullptr, nullptr, nullptr, nullptr, out);
}

// Round 2
// 382.637 us; speedup vs baseline: 1.1166x; 1.1166x over previous
//
#include <hip/hip_runtime.h>
#include <cstdint>

typedef unsigned short ushort_t;
typedef __attribute__((ext_vector_type(8))) short bf16x8;
typedef __attribute__((ext_vector_type(4))) float f32x4;

#define S_LEN 1024
#define DHEAD 64

__device__ inline ushort_t f2bf(float f) {
    union { float f; uint32_t u; } c; c.f = f;
    uint32_t u = c.u;
    uint32_t r = u + 0x7FFFu + ((u >> 16) & 1u);
    return (ushort_t)(r >> 16);
}
__device__ inline float bf2f(ushort_t h) {
    union { uint32_t u; float f; } c; c.u = ((uint32_t)h) << 16;
    return c.f;
}
__device__ inline bf16x8 load8(const ushort_t* p) {
    union { uint4 u; bf16x8 v; } c;
    c.u = *reinterpret_cast<const uint4*>(p);
    return c.v;
}

// ---------------------------------------------------------------------------
// prep: transpose+convert 5 weights (512x512) fp32 -> bf16  W^T at ws[0..]
// ---------------------------------------------------------------------------
__global__ void prep_kernel(const float* __restrict__ wq, const float* __restrict__ wk,
                            const float* __restrict__ wv, const float* __restrict__ wp,
                            const float* __restrict__ wo, ushort_t* __restrict__ ws) {
    int t = blockIdx.x * 256 + threadIdx.x;   // 0..262143
    int wi = blockIdx.y;
    const float* src = wi == 0 ? wq : wi == 1 ? wk : wi == 2 ? wv : wi == 3 ? wp : wo;
    int r = t >> 9, c = t & 511;
    ws[(size_t)wi * 262144 + (size_t)c * 512 + r] = f2bf(src[t]);
}

// ---------------------------------------------------------------------------
// merged projection GEMM: z=0 Q (->Qu,Qv), z=1 K (->Kp), z=2 P (->Pp),
// z=3 V (->Vt transposed [bh][dh][s]). A is fp32, converted during staging.
// out = A[8192x512] @ Wt^T (+bias) scattered per mode.
// ---------------------------------------------------------------------------
__global__ __launch_bounds__(256) void proj_gemm(
    const float* __restrict__ qa, const float* __restrict__ ka,
    const float* __restrict__ va, const float* __restrict__ pa,
    const ushort_t* __restrict__ wT,
    const float* __restrict__ bq, const float* __restrict__ bk,
    const float* __restrict__ bv,
    const float* __restrict__ ub, const float* __restrict__ vb,
    ushort_t* __restrict__ Qu, ushort_t* __restrict__ Qv,
    ushort_t* __restrict__ Kp, ushort_t* __restrict__ Pp,
    ushort_t* __restrict__ Vt) {
    __shared__ ushort_t As[128][72];
    __shared__ ushort_t Bs[128][72];
    int z = blockIdx.z;
    const float* A = z == 0 ? qa : z == 1 ? ka : z == 2 ? pa : va;
    const ushort_t* Bt = wT + (z == 0 ? 0 : z == 1 ? 262144 : z == 2 ? 786432 : 524288);
    const float* bias = z == 0 ? bq : z == 1 ? bk : z == 3 ? bv : nullptr;

    int tid = threadIdx.x;
    int wid = tid >> 6, lane = tid & 63, quad = lane >> 4, l16 = lane & 15;
    int wr = wid >> 1, wc = wid & 1;
    int row0 = blockIdx.y * 128, col0 = blockIdx.x * 128;

    f32x4 acc[4][4];
#pragma unroll
    for (int i = 0; i < 4; i++)
#pragma unroll
        for (int j = 0; j < 4; j++) acc[i][j] = (f32x4){0.f, 0.f, 0.f, 0.f};

    for (int k0 = 0; k0 < 512; k0 += 64) {
#pragma unroll
        for (int i = 0; i < 4; i++) {
            int cid = tid + i * 256;
            int r = cid >> 3, c8 = cid & 7;
            const float* ap = A + (size_t)(row0 + r) * 512 + k0 + c8 * 8;
            float4 f0 = *reinterpret_cast<const float4*>(ap);
            float4 f1 = *reinterpret_cast<const float4*>(ap + 4);
            union { ushort_t s[8]; uint4 u; } pk;
            pk.s[0] = f2bf(f0.x); pk.s[1] = f2bf(f0.y); pk.s[2] = f2bf(f0.z); pk.s[3] = f2bf(f0.w);
            pk.s[4] = f2bf(f1.x); pk.s[5] = f2bf(f1.y); pk.s[6] = f2bf(f1.z); pk.s[7] = f2bf(f1.w);
            *reinterpret_cast<uint4*>(&As[r][c8 * 8]) = pk.u;
            *reinterpret_cast<uint4*>(&Bs[r][c8 * 8]) =
                *reinterpret_cast<const uint4*>(Bt + (size_t)(col0 + r) * 512 + k0 + c8 * 8);
        }
        __syncthreads();
#pragma unroll
        for (int kc = 0; kc < 2; kc++) {
            bf16x8 af[4], bg[4];
#pragma unroll
            for (int m = 0; m < 4; m++)
                af[m] = load8(&As[wr * 64 + m * 16 + l16][kc * 32 + quad * 8]);
#pragma unroll
            for (int n = 0; n < 4; n++)
                bg[n] = load8(&Bs[wc * 64 + n * 16 + l16][kc * 32 + quad * 8]);
#pragma unroll
            for (int m = 0; m < 4; m++)
#pragma unroll
                for (int n = 0; n < 4; n++)
                    acc[m][n] = __builtin_amdgcn_mfma_f32_16x16x32_bf16(af[m], bg[n], acc[m][n], 0, 0, 0);
        }
        __syncthreads();
    }

#pragma unroll
    for (int m = 0; m < 4; m++) {
#pragma unroll
        for (int n = 0; n < 4; n++) {
            int col = col0 + wc * 64 + n * 16 + l16;
            float bcol = bias ? bias[col] : 0.f;
#pragma unroll
            for (int r = 0; r < 4; r++) {
                int row = row0 + wr * 64 + m * 16 + quad * 4 + r;
                float val = acc[m][n][r] + bcol;
                int b_ = row >> 10, s_ = row & 1023, h_ = col >> 6, d_ = col & 63;
                if (z == 0) {
                    size_t idx = (((size_t)(b_ * 8 + h_)) * 1024 + s_) * 64 + d_;
                    Qu[idx] = f2bf(val + ub[col]);
                    Qv[idx] = f2bf(val + vb[col]);
                } else if (z == 3) {
                    size_t idx = (((size_t)(b_ * 8 + h_)) * 64 + d_) * 1024 + s_;
                    Vt[idx] = f2bf(val);
                } else {
                    size_t idx = (((size_t)(b_ * 8 + h_)) * 1024 + s_) * 64 + d_;
                    (z == 1 ? Kp : Pp)[idx] = f2bf(val);
                }
            }
        }
    }
}

// ---------------------------------------------------------------------------
// out-proj: ctx[8192x512]bf16 @ Wo^T + bo -> fp32 out
// ---------------------------------------------------------------------------
__global__ __launch_bounds__(256) void out_gemm(
    const ushort_t* __restrict__ A, const ushort_t* __restrict__ Bt,
    const float* __restrict__ bias, float* __restrict__ outf) {
    __shared__ ushort_t As[128][72];
    __shared__ ushort_t Bs[128][72];
    int tid = threadIdx.x;
    int wid = tid >> 6, lane = tid & 63, quad = lane >> 4, l16 = lane & 15;
    int wr = wid >> 1, wc = wid & 1;
    int row0 = blockIdx.y * 128, col0 = blockIdx.x * 128;

    f32x4 acc[4][4];
#pragma unroll
    for (int i = 0; i < 4; i++)
#pragma unroll
        for (int j = 0; j < 4; j++) acc[i][j] = (f32x4){0.f, 0.f, 0.f, 0.f};

    for (int k0 = 0; k0 < 512; k0 += 64) {
#pragma unroll
        for (int i = 0; i < 4; i++) {
            int cid = tid + i * 256;
            int r = cid >> 3, c8 = cid & 7;
            *reinterpret_cast<uint4*>(&As[r][c8 * 8]) =
                *reinterpret_cast<const uint4*>(A + (size_t)(row0 + r) * 512 + k0 + c8 * 8);
            *reinterpret_cast<uint4*>(&Bs[r][c8 * 8]) =
                *reinterpret_cast<const uint4*>(Bt + (size_t)(col0 + r) * 512 + k0 + c8 * 8);
        }
        __syncthreads();
#pragma unroll
        for (int kc = 0; kc < 2; kc++) {
            bf16x8 af[4], bg[4];
#pragma unroll
            for (int m = 0; m < 4; m++)
                af[m] = load8(&As[wr * 64 + m * 16 + l16][kc * 32 + quad * 8]);
#pragma unroll
            for (int n = 0; n < 4; n++)
                bg[n] = load8(&Bs[wc * 64 + n * 16 + l16][kc * 32 + quad * 8]);
#pragma unroll
            for (int m = 0; m < 4; m++)
#pragma unroll
                for (int n = 0; n < 4; n++)
                    acc[m][n] = __builtin_amdgcn_mfma_f32_16x16x32_bf16(af[m], bg[n], acc[m][n], 0, 0, 0);
        }
        __syncthreads();
    }
#pragma unroll
    for (int m = 0; m < 4; m++)
#pragma unroll
        for (int n = 0; n < 4; n++) {
            int col = col0 + wc * 64 + n * 16 + l16;
#pragma unroll
            for (int r = 0; r < 4; r++) {
                int row = row0 + wr * 64 + m * 16 + quad * 4 + r;
                outf[(size_t)row * 512 + col] = acc[m][n][r] + bias[col];
            }
        }
}

// ---------------------------------------------------------------------------
// Fused attention v2: block = (bh, 16 q-rows), 4 waves split k 256 each.
// Phase 1: pos scores scatter-WRITTEN (branch1 k<=q, branch2 k>=q+2, zero
//          at k=q+1 — exact partition of k, no read-modify-write).
// Phase 2: content MFMA consumes pos tile as C operand, writes final raw
//          scores; row-max tracked in registers (shfl-xor reduce in quad).
// Phase 3: vectorized softmax (b128), thread (row=tid&15, cb=tid>>4) owns
//          64 cols = its own wave's k-range. 2 barriers total.
// Phase 4: PV MFMA (wave w owns d-cols [16w,16w+16)), normalize by row sum.
// ---------------------------------------------------------------------------
__global__ __launch_bounds__(256) void attn_kernel(
    const ushort_t* __restrict__ Qu, const ushort_t* __restrict__ Qv,
    const ushort_t* __restrict__ Kp, const ushort_t* __restrict__ Pp,
    const ushort_t* __restrict__ Vt, ushort_t* __restrict__ ctxb) {
    __shared__ ushort_t sc[16][1032];   // stride 1032 ushort = 516 dw ≡ 4 banks
    __shared__ float red1[4][16];       // per-wave partial row max
    __shared__ float red2[4][16];       // per-wave partial row expsum

    constexpr float SCL = (float)(1.4426950408889634 / 22.627416997969522); // log2(e)/sqrt(512)

    int bx = blockIdx.x;
    int bh = bx >> 6, q0 = (bx & 63) << 4;
    int tid = threadIdx.x, wid = tid >> 6, lane = tid & 63;
    int quad = lane >> 4, l16 = lane & 15;

    const ushort_t* Qu_b = Qu + (size_t)bh * S_LEN * DHEAD;
    const ushort_t* Qv_b = Qv + (size_t)bh * S_LEN * DHEAD;
    const ushort_t* K_b  = Kp + (size_t)bh * S_LEN * DHEAD;
    const ushort_t* P_b  = Pp + (size_t)bh * S_LEN * DHEAD;
    const ushort_t* V_b  = Vt + (size_t)bh * DHEAD * S_LEN;

    bf16x8 au[2], av1[2], av2[2];
#pragma unroll
    for (int kc = 0; kc < 2; kc++) {
        au[kc]  = load8(Qu_b + (size_t)(q0 + l16) * 64 + kc * 32 + quad * 8);
        av1[kc] = load8(Qv_b + (size_t)(q0 + l16) * 64 + kc * 32 + quad * 8);
        int r2 = q0 + 1 + l16; if (r2 > S_LEN - 1) r2 = S_LEN - 1;
        av2[kc] = load8(Qv_b + (size_t)r2 * 64 + kc * 32 + quad * 8);
    }

    int kw0 = wid << 8, kw1 = kw0 + 256;

    // zero-fill k = q+1 inside this wave's range
    if (lane < 16) {
        int kz = q0 + lane + 1;
        if (kz >= kw0 && kz < kw1) sc[lane][kz] = 0;
    }

    // ---- pos branch 1: k <= q, scatter-write ----
    if (kw0 <= q0 + 15) {
        int wlo = (S_LEN - 16) - q0 + kw0;
        int d1 = kw1 - 1 - q0; if (d1 > 0) d1 = 0;
        int whi = (S_LEN - 1) + d1;
        for (int wt = wlo; wt <= whi; wt += 16) {
            int prow = wt + l16; if (prow > S_LEN - 1) prow = S_LEN - 1;
            bf16x8 b0 = load8(P_b + (size_t)prow * 64 + quad * 8);
            bf16x8 b1 = load8(P_b + (size_t)prow * 64 + 32 + quad * 8);
            f32x4 acc = (f32x4){0.f, 0.f, 0.f, 0.f};
            acc = __builtin_amdgcn_mfma_f32_16x16x32_bf16(av1[0], b0, acc, 0, 0, 0);
            acc = __builtin_amdgcn_mfma_f32_16x16x32_bf16(av1[1], b1, acc, 0, 0, 0);
#pragma unroll
            for (int r = 0; r < 4; r++) {
                int m = quad * 4 + r, q = q0 + m;
                int k = wt + l16 - (S_LEN - 1) + q;
                if (k >= kw0 && k < kw1 && k <= q) sc[m][k] = f2bf(acc[r]);
            }
        }
    }
    // ---- pos branch 2: k >= q+2, scatter-write ----
    if (kw1 - 1 >= q0 + 2) {
        int wlo2 = kw0 - q0 - 17; if (wlo2 < 0) wlo2 = 0;
        int whi2 = kw1 - 3 - q0;
        for (int wt = wlo2; wt <= whi2; wt += 16) {
            int prow = wt + l16; if (prow > S_LEN - 1) prow = S_LEN - 1;
            bf16x8 b0 = load8(P_b + (size_t)prow * 64 + quad * 8);
            bf16x8 b1 = load8(P_b + (size_t)prow * 64 + 32 + quad * 8);
            f32x4 acc = (f32x4){0.f, 0.f, 0.f, 0.f};
            acc = __builtin_amdgcn_mfma_f32_16x16x32_bf16(av2[0], b0, acc, 0, 0, 0);
            acc = __builtin_amdgcn_mfma_f32_16x16x32_bf16(av2[1], b1, acc, 0, 0, 0);
#pragma unroll
            for (int r = 0; r < 4; r++) {
                int m = quad * 4 + r, q = q0 + m;
                int k = wt + l16 + q + 2;
                if (k >= kw0 && k < kw1) sc[m][k] = f2bf(acc[r]);
            }
        }
    }

    // ---- content pass: C operand = pos tile from LDS; track row max ----
    float pm[4] = {-1e30f, -1e30f, -1e30f, -1e30f};
    for (int nt = 0; nt < 16; ++nt) {
        int kt = kw0 + nt * 16;
        bf16x8 b0 = load8(K_b + (size_t)(kt + l16) * 64 + quad * 8);
        bf16x8 b1 = load8(K_b + (size_t)(kt + l16) * 64 + 32 + quad * 8);
        f32x4 acc;
#pragma unroll
        for (int r = 0; r < 4; r++) acc[r] = bf2f(sc[quad * 4 + r][kt + l16]);
        acc = __builtin_amdgcn_mfma_f32_16x16x32_bf16(au[0], b0, acc, 0, 0, 0);
        acc = __builtin_amdgcn_mfma_f32_16x16x32_bf16(au[1], b1, acc, 0, 0, 0);
#pragma unroll
        for (int r = 0; r < 4; r++) {
            sc[quad * 4 + r][kt + l16] = f2bf(acc[r]);
            pm[r] = fmaxf(pm[r], acc[r]);
        }
    }
    // reduce row max across the 16 lanes of each quad
#pragma unroll
    for (int off = 1; off < 16; off <<= 1)
#pragma unroll
        for (int r = 0; r < 4; r++) pm[r] = fmaxf(pm[r], __shfl_xor(pm[r], off));
    if (l16 == 0) {
#pragma unroll
        for (int r = 0; r < 4; r++) red1[wid][quad * 4 + r] = pm[r];
    }
    __syncthreads();   // barrier 1

    // ---- softmax: thread (row = tid&15, cb = tid>>4) owns cols [cb*64,+64) ----
    int row = tid & 15, cb = tid >> 4;
    float rm = fmaxf(fmaxf(red1[0][row], red1[1][row]), fmaxf(red1[2][row], red1[3][row]));
    float ssum = 0.f;
    ushort_t* sp = &sc[row][cb * 64];
#pragma unroll
    for (int j = 0; j < 8; j++) {
        union { uint4 u; ushort_t s[8]; } in, out;
        in.u = *reinterpret_cast<uint4*>(sp + j * 8);
#pragma unroll
        for (int e = 0; e < 8; e++) {
            float ev = exp2f((bf2f(in.s[e]) - rm) * SCL);
            out.s[e] = f2bf(ev);
            ssum += ev;
        }
        *reinterpret_cast<uint4*>(sp + j * 8) = out.u;
    }
    ssum += __shfl_xor(ssum, 16);
    ssum += __shfl_xor(ssum, 32);
    if (lane < 16) red2[wid][lane] = ssum;
    __syncthreads();   // barrier 2

    // ---- PV: wave w owns d-cols [16w, 16w+16), K = 1024 ----
    int d0 = wid << 4;
    f32x4 acc = (f32x4){0.f, 0.f, 0.f, 0.f};
    for (int kc = 0; kc < 32; ++kc) {
        bf16x8 a = load8(&sc[l16][kc * 32 + quad * 8]);
        bf16x8 b = load8(V_b + (size_t)(d0 + l16) * 1024 + kc * 32 + quad * 8);
        acc = __builtin_amdgcn_mfma_f32_16x16x32_bf16(a, b, acc, 0, 0, 0);
    }
    int b_ = bh >> 3, h_ = bh & 7;
#pragma unroll
    for (int r = 0; r < 4; r++) {
        int m = quad * 4 + r, q = q0 + m;
        float s = red2[0][m] + red2[1][m] + red2[2][m] + red2[3][m];
        ctxb[((size_t)b_ * 1024 + q) * 512 + h_ * 64 + d0 + l16] = f2bf(acc[r] / s);
    }
}

extern "C" void kernel_launch(void* const* d_in, const int* in_sizes, int n_in,
                              void* d_out, int out_size, void* d_ws, size_t ws_size,
                              hipStream_t stream) {
    const float* q  = (const float*)d_in[0];
    const float* k  = (const float*)d_in[1];
    const float* v  = (const float*)d_in[2];
    const float* pe = (const float*)d_in[3];
    const float* Wq = (const float*)d_in[4];
    const float* bq = (const float*)d_in[5];
    const float* Wk = (const float*)d_in[6];
    const float* bk = (const float*)d_in[7];
    const float* Wv = (const float*)d_in[8];
    const float* bv = (const float*)d_in[9];
    const float* Wp = (const float*)d_in[10];
    const float* ub = (const float*)d_in[11];
    const float* vbias = (const float*)d_in[12];
    const float* Wo = (const float*)d_in[13];
    const float* bo = (const float*)d_in[14];
    float* out = (float*)d_out;
    ushort_t* ws = (ushort_t*)d_ws;

    // ws map (ushort elems), total ~53 MB
    ushort_t* wT  = ws;                       // 5 x 262144
    ushort_t* Qu  = ws + 1310720;
    ushort_t* Qv  = Qu + 4194304;
    ushort_t* Kp  = Qv + 4194304;
    ushort_t* Pp  = Kp + 4194304;
    ushort_t* Vt  = Pp + 4194304;
    ushort_t* ctx = Vt + 4194304;

    prep_kernel<<<dim3(1024, 5), 256, 0, stream>>>(Wq, Wk, Wv, Wp, Wo, wT);
    proj_gemm<<<dim3(4, 64, 4), 256, 0, stream>>>(q, k, v, pe, wT, bq, bk, bv,
                                                  ub, vbias, Qu, Qv, Kp, Pp, Vt);
    attn_kernel<<<4096, 256, 0, stream>>>(Qu, Qv, Kp, Pp, Vt, ctx);
    out_gemm<<<dim3(4, 64), 256, 0, stream>>>(ctx, wT + 4 * 262144, bo, out);
}

// Round 3
// 337.442 us; speedup vs baseline: 1.2661x; 1.1339x over previous
//
#include <hip/hip_runtime.h>
#include <cstdint>

typedef unsigned short ushort_t;
typedef __attribute__((ext_vector_type(8))) short bf16x8;
typedef __attribute__((ext_vector_type(4))) float f32x4;

#define S_LEN 1024
#define DHEAD 64

__device__ inline ushort_t f2bf(float f) {
    union { float f; uint32_t u; } c; c.f = f;
    uint32_t u = c.u;
    uint32_t r = u + 0x7FFFu + ((u >> 16) & 1u);
    return (ushort_t)(r >> 16);
}
__device__ inline float bf2f(ushort_t h) {
    union { uint32_t u; float f; } c; c.u = ((uint32_t)h) << 16;
    return c.f;
}
__device__ inline bf16x8 load8(const ushort_t* p) {
    union { uint4 u; bf16x8 v; } c;
    c.u = *reinterpret_cast<const uint4*>(p);
    return c.v;
}

// ---------------------------------------------------------------------------
// prep: tiled transpose+convert 5 weights (512x512) fp32 -> bf16 W^T
// 64x64 tiles through LDS; coalesced ushort4 stores.
// ---------------------------------------------------------------------------
__global__ __launch_bounds__(256) void prep_kernel(
    const float* __restrict__ wq, const float* __restrict__ wk,
    const float* __restrict__ wv, const float* __restrict__ wp,
    const float* __restrict__ wo, ushort_t* __restrict__ ws) {
    __shared__ float tile[64][65];
    int wi = blockIdx.z;
    const float* src = wi == 0 ? wq : wi == 1 ? wk : wi == 2 ? wv : wi == 3 ? wp : wo;
    int cx = blockIdx.x * 64;   // source col base
    int ry = blockIdx.y * 64;   // source row base
    int t = threadIdx.x;
    int tr = t >> 4;            // 0..15
    int tc = (t & 15) * 4;      // 0..60
#pragma unroll
    for (int i = 0; i < 4; i++) {
        int r = tr + i * 16;
        float4 f = *reinterpret_cast<const float4*>(src + (size_t)(ry + r) * 512 + cx + tc);
        tile[r][tc] = f.x; tile[r][tc + 1] = f.y; tile[r][tc + 2] = f.z; tile[r][tc + 3] = f.w;
    }
    __syncthreads();
    ushort_t* dst = ws + (size_t)wi * 262144;
#pragma unroll
    for (int i = 0; i < 4; i++) {
        int r = tr + i * 16;    // output row within tile = source col
        ushort4 o;
        o.x = f2bf(tile[tc][r]); o.y = f2bf(tile[tc + 1][r]);
        o.z = f2bf(tile[tc + 2][r]); o.w = f2bf(tile[tc + 3][r]);
        *reinterpret_cast<ushort4*>(dst + (size_t)(cx + r) * 512 + ry + tc) = o;
    }
}

// ---------------------------------------------------------------------------
// merged projection GEMM: z=0 Q (->Qu,Qv), z=1 K (->Kp), z=2 P (->Pp),
// z=3 V (->Vt transposed [bh][dh][s] via LDS transpose, coalesced stores).
// ---------------------------------------------------------------------------
__global__ __launch_bounds__(256) void proj_gemm(
    const float* __restrict__ qa, const float* __restrict__ ka,
    const float* __restrict__ va, const float* __restrict__ pa,
    const ushort_t* __restrict__ wT,
    const float* __restrict__ bq, const float* __restrict__ bk,
    const float* __restrict__ bv,
    const float* __restrict__ ub, const float* __restrict__ vb,
    ushort_t* __restrict__ Qu, ushort_t* __restrict__ Qv,
    ushort_t* __restrict__ Kp, ushort_t* __restrict__ Pp,
    ushort_t* __restrict__ Vt) {
    __shared__ ushort_t smem[2][128][72];
    int z = blockIdx.z;
    const float* A = z == 0 ? qa : z == 1 ? ka : z == 2 ? pa : va;
    const ushort_t* Bt = wT + (z == 0 ? 0 : z == 1 ? 262144 : z == 2 ? 786432 : 524288);
    const float* bias = z == 0 ? bq : z == 1 ? bk : z == 3 ? bv : nullptr;

    int tid = threadIdx.x;
    int wid = tid >> 6, lane = tid & 63, quad = lane >> 4, l16 = lane & 15;
    int wr = wid >> 1, wc = wid & 1;
    int row0 = blockIdx.y * 128, col0 = blockIdx.x * 128;

    f32x4 acc[4][4];
#pragma unroll
    for (int i = 0; i < 4; i++)
#pragma unroll
        for (int j = 0; j < 4; j++) acc[i][j] = (f32x4){0.f, 0.f, 0.f, 0.f};

    for (int k0 = 0; k0 < 512; k0 += 64) {
#pragma unroll
        for (int i = 0; i < 4; i++) {
            int cid = tid + i * 256;
            int r = cid >> 3, c8 = cid & 7;
            const float* ap = A + (size_t)(row0 + r) * 512 + k0 + c8 * 8;
            float4 f0 = *reinterpret_cast<const float4*>(ap);
            float4 f1 = *reinterpret_cast<const float4*>(ap + 4);
            union { ushort_t s[8]; uint4 u; } pk;
            pk.s[0] = f2bf(f0.x); pk.s[1] = f2bf(f0.y); pk.s[2] = f2bf(f0.z); pk.s[3] = f2bf(f0.w);
            pk.s[4] = f2bf(f1.x); pk.s[5] = f2bf(f1.y); pk.s[6] = f2bf(f1.z); pk.s[7] = f2bf(f1.w);
            *reinterpret_cast<uint4*>(&smem[0][r][c8 * 8]) = pk.u;
            *reinterpret_cast<uint4*>(&smem[1][r][c8 * 8]) =
                *reinterpret_cast<const uint4*>(Bt + (size_t)(col0 + r) * 512 + k0 + c8 * 8);
        }
        __syncthreads();
#pragma unroll
        for (int kc = 0; kc < 2; kc++) {
            bf16x8 af[4], bg[4];
#pragma unroll
            for (int m = 0; m < 4; m++)
                af[m] = load8(&smem[0][wr * 64 + m * 16 + l16][kc * 32 + quad * 8]);
#pragma unroll
            for (int n = 0; n < 4; n++)
                bg[n] = load8(&smem[1][wc * 64 + n * 16 + l16][kc * 32 + quad * 8]);
#pragma unroll
            for (int m = 0; m < 4; m++)
#pragma unroll
                for (int n = 0; n < 4; n++)
                    acc[m][n] = __builtin_amdgcn_mfma_f32_16x16x32_bf16(af[m], bg[n], acc[m][n], 0, 0, 0);
        }
        __syncthreads();
    }

    if (z == 3) {
        // transpose tile through LDS, then coalesced stores to Vt[bh][dh][s]
        ushort_t (*Ts)[130] = reinterpret_cast<ushort_t(*)[130]>(&smem[0][0][0]);
#pragma unroll
        for (int m = 0; m < 4; m++)
#pragma unroll
            for (int n = 0; n < 4; n++) {
                int dl = wc * 64 + n * 16 + l16;
                float bcol = bv[col0 + dl];
#pragma unroll
                for (int r = 0; r < 4; r++) {
                    int sl = wr * 64 + m * 16 + quad * 4 + r;
                    Ts[dl][sl] = f2bf(acc[m][n][r] + bcol);
                }
            }
        __syncthreads();
        int b_ = row0 >> 10, s0 = row0 & 1023;
#pragma unroll
        for (int p = 0; p < 8; p++) {
            int dl = p * 16 + (tid >> 4);
            int sl = (tid & 15) * 8;
            int col = col0 + dl, h_ = col >> 6, d_ = col & 63;
            ushort_t* dst = Vt + (((size_t)(b_ * 8 + h_)) * 64 + d_) * 1024 + s0 + sl;
            union { uint4 u; ushort_t s[8]; } pk;
#pragma unroll
            for (int e = 0; e < 8; e++) pk.s[e] = Ts[dl][sl + e];
            *reinterpret_cast<uint4*>(dst) = pk.u;
        }
    } else {
#pragma unroll
        for (int m = 0; m < 4; m++)
#pragma unroll
            for (int n = 0; n < 4; n++) {
                int col = col0 + wc * 64 + n * 16 + l16;
                float bcol = bias ? bias[col] : 0.f;
#pragma unroll
                for (int r = 0; r < 4; r++) {
                    int row = row0 + wr * 64 + m * 16 + quad * 4 + r;
                    float val = acc[m][n][r] + bcol;
                    int b_ = row >> 10, s_ = row & 1023, h_ = col >> 6, d_ = col & 63;
                    size_t idx = (((size_t)(b_ * 8 + h_)) * 1024 + s_) * 64 + d_;
                    if (z == 0) {
                        Qu[idx] = f2bf(val + ub[col]);
                        Qv[idx] = f2bf(val + vb[col]);
                    } else {
                        (z == 1 ? Kp : Pp)[idx] = f2bf(val);
                    }
                }
            }
    }
}

// ---------------------------------------------------------------------------
// out-proj: ctx[8192x512]bf16 @ Wo^T + bo -> fp32 out
// ---------------------------------------------------------------------------
__global__ __launch_bounds__(256) void out_gemm(
    const ushort_t* __restrict__ A, const ushort_t* __restrict__ Bt,
    const float* __restrict__ bias, float* __restrict__ outf) {
    __shared__ ushort_t As[128][72];
    __shared__ ushort_t Bs[128][72];
    int tid = threadIdx.x;
    int wid = tid >> 6, lane = tid & 63, quad = lane >> 4, l16 = lane & 15;
    int wr = wid >> 1, wc = wid & 1;
    int row0 = blockIdx.y * 128, col0 = blockIdx.x * 128;

    f32x4 acc[4][4];
#pragma unroll
    for (int i = 0; i < 4; i++)
#pragma unroll
        for (int j = 0; j < 4; j++) acc[i][j] = (f32x4){0.f, 0.f, 0.f, 0.f};

    for (int k0 = 0; k0 < 512; k0 += 64) {
#pragma unroll
        for (int i = 0; i < 4; i++) {
            int cid = tid + i * 256;
            int r = cid >> 3, c8 = cid & 7;
            *reinterpret_cast<uint4*>(&As[r][c8 * 8]) =
                *reinterpret_cast<const uint4*>(A + (size_t)(row0 + r) * 512 + k0 + c8 * 8);
            *reinterpret_cast<uint4*>(&Bs[r][c8 * 8]) =
                *reinterpret_cast<const uint4*>(Bt + (size_t)(col0 + r) * 512 + k0 + c8 * 8);
        }
        __syncthreads();
#pragma unroll
        for (int kc = 0; kc < 2; kc++) {
            bf16x8 af[4], bg[4];
#pragma unroll
            for (int m = 0; m < 4; m++)
                af[m] = load8(&As[wr * 64 + m * 16 + l16][kc * 32 + quad * 8]);
#pragma unroll
            for (int n = 0; n < 4; n++)
                bg[n] = load8(&Bs[wc * 64 + n * 16 + l16][kc * 32 + quad * 8]);
#pragma unroll
            for (int m = 0; m < 4; m++)
#pragma unroll
                for (int n = 0; n < 4; n++)
                    acc[m][n] = __builtin_amdgcn_mfma_f32_16x16x32_bf16(af[m], bg[n], acc[m][n], 0, 0, 0);
        }
        __syncthreads();
    }
#pragma unroll
    for (int m = 0; m < 4; m++)
#pragma unroll
        for (int n = 0; n < 4; n++) {
            int col = col0 + wc * 64 + n * 16 + l16;
#pragma unroll
            for (int r = 0; r < 4; r++) {
                int row = row0 + wr * 64 + m * 16 + quad * 4 + r;
                outf[(size_t)row * 512 + col] = acc[m][n][r] + bias[col];
            }
        }
}

// ---------------------------------------------------------------------------
// Fused attention v3: block = (bh, 32 q-rows), grid 2048, 4 waves (k-range
// 256 each). K/V tiles loaded once feed BOTH 16-row m-tiles; explicit
// register double-buffer prefetch in content/pos/PV loops.
// ---------------------------------------------------------------------------
__global__ __launch_bounds__(256) void attn_kernel(
    const ushort_t* __restrict__ Qu, const ushort_t* __restrict__ Qv,
    const ushort_t* __restrict__ Kp, const ushort_t* __restrict__ Pp,
    const ushort_t* __restrict__ Vt, ushort_t* __restrict__ ctxb) {
    __shared__ ushort_t sc[32][1032];   // 66 KB; stride 516 dw == 4 banks
    __shared__ float red1[4][32];
    __shared__ float red2[32][8];
    __shared__ float rowinv[32];

    constexpr float SCL = (float)(1.4426950408889634 / 22.627416997969522);

    int bx = blockIdx.x;
    int bh = bx >> 5, q0 = (bx & 31) << 5;
    int tid = threadIdx.x, wid = tid >> 6, lane = tid & 63;
    int quad = lane >> 4, l16 = lane & 15;

    const ushort_t* Qu_b = Qu + (size_t)bh * S_LEN * DHEAD;
    const ushort_t* Qv_b = Qv + (size_t)bh * S_LEN * DHEAD;
    const ushort_t* K_b  = Kp + (size_t)bh * S_LEN * DHEAD;
    const ushort_t* P_b  = Pp + (size_t)bh * S_LEN * DHEAD;
    const ushort_t* V_b  = Vt + (size_t)bh * DHEAD * S_LEN;

    int kw0 = wid << 8, kw1 = kw0 + 256;

    // content A-frags for both m-tiles (issue early)
    bf16x8 au0[2], au1[2];
#pragma unroll
    for (int kc = 0; kc < 2; kc++) {
        au0[kc] = load8(Qu_b + (size_t)(q0 + l16) * 64 + kc * 32 + quad * 8);
        au1[kc] = load8(Qu_b + (size_t)(q0 + 16 + l16) * 64 + kc * 32 + quad * 8);
    }

    // zero-fill k = q+1 inside this wave's range (rows 0..31)
    if (lane < 32) {
        int kz = q0 + lane + 1;
        if (kz >= kw0 && kz < kw1) sc[lane][kz] = 0;
    }

    // ---- pos scores, scatter-write, both m-tiles ----
#pragma unroll
    for (int mt = 0; mt < 2; mt++) {
        int q0m = q0 + mt * 16;
        bf16x8 av1[2], av2[2];
#pragma unroll
        for (int kc = 0; kc < 2; kc++) {
            av1[kc] = load8(Qv_b + (size_t)(q0m + l16) * 64 + kc * 32 + quad * 8);
            int r2 = q0m + 1 + l16; if (r2 > S_LEN - 1) r2 = S_LEN - 1;
            av2[kc] = load8(Qv_b + (size_t)r2 * 64 + kc * 32 + quad * 8);
        }
        // branch 1: k <= q
        if (kw0 <= q0m + 15) {
            int wlo = (S_LEN - 16) - q0m + kw0;
            int d1 = kw1 - 1 - q0m; if (d1 > 0) d1 = 0;
            int whi = (S_LEN - 1) + d1;
            int pr = wlo + l16; if (pr > S_LEN - 1) pr = S_LEN - 1;
            bf16x8 p0 = load8(P_b + (size_t)pr * 64 + quad * 8);
            bf16x8 p1 = load8(P_b + (size_t)pr * 64 + 32 + quad * 8);
            for (int wt = wlo; wt <= whi; wt += 16) {
                bf16x8 b0 = p0, b1 = p1;
                if (wt + 16 <= whi) {
                    int pn = wt + 16 + l16; if (pn > S_LEN - 1) pn = S_LEN - 1;
                    p0 = load8(P_b + (size_t)pn * 64 + quad * 8);
                    p1 = load8(P_b + (size_t)pn * 64 + 32 + quad * 8);
                }
                f32x4 acc = (f32x4){0.f, 0.f, 0.f, 0.f};
                acc = __builtin_amdgcn_mfma_f32_16x16x32_bf16(av1[0], b0, acc, 0, 0, 0);
                acc = __builtin_amdgcn_mfma_f32_16x16x32_bf16(av1[1], b1, acc, 0, 0, 0);
#pragma unroll
                for (int r = 0; r < 4; r++) {
                    int m = quad * 4 + r, q = q0m + m;
                    int k = wt + l16 - (S_LEN - 1) + q;
                    if (k >= kw0 && k < kw1 && k <= q) sc[mt * 16 + m][k] = f2bf(acc[r]);
                }
            }
        }
        // branch 2: k >= q+2
        if (kw1 - 1 >= q0m + 2) {
            int wlo2 = kw0 - q0m - 17; if (wlo2 < 0) wlo2 = 0;
            int whi2 = kw1 - 3 - q0m;
            int pr = wlo2 + l16; if (pr > S_LEN - 1) pr = S_LEN - 1;
            bf16x8 p0 = load8(P_b + (size_t)pr * 64 + quad * 8);
            bf16x8 p1 = load8(P_b + (size_t)pr * 64 + 32 + quad * 8);
            for (int wt = wlo2; wt <= whi2; wt += 16) {
                bf16x8 b0 = p0, b1 = p1;
                if (wt + 16 <= whi2) {
                    int pn = wt + 16 + l16; if (pn > S_LEN - 1) pn = S_LEN - 1;
                    p0 = load8(P_b + (size_t)pn * 64 + quad * 8);
                    p1 = load8(P_b + (size_t)pn * 64 + 32 + quad * 8);
                }
                f32x4 acc = (f32x4){0.f, 0.f, 0.f, 0.f};
                acc = __builtin_amdgcn_mfma_f32_16x16x32_bf16(av2[0], b0, acc, 0, 0, 0);
                acc = __builtin_amdgcn_mfma_f32_16x16x32_bf16(av2[1], b1, acc, 0, 0, 0);
#pragma unroll
                for (int r = 0; r < 4; r++) {
                    int m = quad * 4 + r, q = q0m + m;
                    int k = wt + l16 + q + 2;
                    if (k >= kw0 && k < kw1) sc[mt * 16 + m][k] = f2bf(acc[r]);
                }
            }
        }
    }

    // ---- content pass: shared K tile feeds both m-tiles; C = pos from LDS ----
    float pm0[4] = {-1e30f, -1e30f, -1e30f, -1e30f};
    float pm1[4] = {-1e30f, -1e30f, -1e30f, -1e30f};
    const ushort_t* Kw = K_b + (size_t)kw0 * 64;
    bf16x8 k0 = load8(Kw + (size_t)l16 * 64 + quad * 8);
    bf16x8 k1 = load8(Kw + (size_t)l16 * 64 + 32 + quad * 8);
    for (int nt = 0; nt < 16; ++nt) {
        int kt = kw0 + nt * 16;
        bf16x8 b0 = k0, b1 = k1;
        if (nt < 15) {
            const ushort_t* kp = Kw + (size_t)((nt + 1) * 16 + l16) * 64;
            k0 = load8(kp + quad * 8);
            k1 = load8(kp + 32 + quad * 8);
        }
        f32x4 a0, a1;
#pragma unroll
        for (int r = 0; r < 4; r++) {
            a0[r] = bf2f(sc[quad * 4 + r][kt + l16]);
            a1[r] = bf2f(sc[16 + quad * 4 + r][kt + l16]);
        }
        a0 = __builtin_amdgcn_mfma_f32_16x16x32_bf16(au0[0], b0, a0, 0, 0, 0);
        a0 = __builtin_amdgcn_mfma_f32_16x16x32_bf16(au0[1], b1, a0, 0, 0, 0);
        a1 = __builtin_amdgcn_mfma_f32_16x16x32_bf16(au1[0], b0, a1, 0, 0, 0);
        a1 = __builtin_amdgcn_mfma_f32_16x16x32_bf16(au1[1], b1, a1, 0, 0, 0);
#pragma unroll
        for (int r = 0; r < 4; r++) {
            sc[quad * 4 + r][kt + l16] = f2bf(a0[r]);
            sc[16 + quad * 4 + r][kt + l16] = f2bf(a1[r]);
            pm0[r] = fmaxf(pm0[r], a0[r]);
            pm1[r] = fmaxf(pm1[r], a1[r]);
        }
    }
#pragma unroll
    for (int off = 1; off < 16; off <<= 1)
#pragma unroll
        for (int r = 0; r < 4; r++) {
            pm0[r] = fmaxf(pm0[r], __shfl_xor(pm0[r], off));
            pm1[r] = fmaxf(pm1[r], __shfl_xor(pm1[r], off));
        }
    if (l16 == 0) {
#pragma unroll
        for (int r = 0; r < 4; r++) {
            red1[wid][quad * 4 + r] = pm0[r];
            red1[wid][16 + quad * 4 + r] = pm1[r];
        }
    }
    __syncthreads();   // B1

    // ---- softmax: thread (row=tid&31, cb=tid>>5) owns cols [cb*128,+128) ----
    int row = tid & 31, cb = tid >> 5;
    float rm = fmaxf(fmaxf(red1[0][row], red1[1][row]), fmaxf(red1[2][row], red1[3][row]));
    float ssum = 0.f;
    ushort_t* sp = &sc[row][cb * 128];
#pragma unroll
    for (int j = 0; j < 16; j++) {
        union { uint4 u; ushort_t s[8]; } in, out;
        in.u = *reinterpret_cast<uint4*>(sp + j * 8);
#pragma unroll
        for (int e = 0; e < 8; e++) {
            float ev = exp2f((bf2f(in.s[e]) - rm) * SCL);
            out.s[e] = f2bf(ev);
            ssum += ev;
        }
        *reinterpret_cast<uint4*>(sp + j * 8) = out.u;
    }
    red2[row][cb] = ssum;
    __syncthreads();   // B2
    if (tid < 32) {
        float s = 0.f;
#pragma unroll
        for (int c = 0; c < 8; c++) s += red2[tid][c];
        rowinv[tid] = 1.0f / s;
    }

    // ---- PV: wave owns d-cols [16w,+16); V load feeds both m-tiles ----
    int d0 = wid << 4;
    const ushort_t* Vw = V_b + (size_t)(d0 + l16) * 1024;
    bf16x8 vb0 = load8(Vw + quad * 8);
    f32x4 ac0 = (f32x4){0.f, 0.f, 0.f, 0.f};
    f32x4 ac1 = (f32x4){0.f, 0.f, 0.f, 0.f};
    for (int kc = 0; kc < 32; ++kc) {
        bf16x8 b = vb0;
        if (kc < 31) vb0 = load8(Vw + (kc + 1) * 32 + quad * 8);
        bf16x8 a0 = load8(&sc[l16][kc * 32 + quad * 8]);
        bf16x8 a1 = load8(&sc[16 + l16][kc * 32 + quad * 8]);
        ac0 = __builtin_amdgcn_mfma_f32_16x16x32_bf16(a0, b, ac0, 0, 0, 0);
        ac1 = __builtin_amdgcn_mfma_f32_16x16x32_bf16(a1, b, ac1, 0, 0, 0);
    }
    __syncthreads();   // B3 (rowinv visibility)
    int b_ = bh >> 3, h_ = bh & 7;
#pragma unroll
    for (int r = 0; r < 4; r++) {
        int m = quad * 4 + r;
        ctxb[((size_t)b_ * 1024 + (q0 + m)) * 512 + h_ * 64 + d0 + l16] =
            f2bf(ac0[r] * rowinv[m]);
        ctxb[((size_t)b_ * 1024 + (q0 + 16 + m)) * 512 + h_ * 64 + d0 + l16] =
            f2bf(ac1[r] * rowinv[16 + m]);
    }
}

extern "C" void kernel_launch(void* const* d_in, const int* in_sizes, int n_in,
                              void* d_out, int out_size, void* d_ws, size_t ws_size,
                              hipStream_t stream) {
    const float* q  = (const float*)d_in[0];
    const float* k  = (const float*)d_in[1];
    const float* v  = (const float*)d_in[2];
    const float* pe = (const float*)d_in[3];
    const float* Wq = (const float*)d_in[4];
    const float* bq = (const float*)d_in[5];
    const float* Wk = (const float*)d_in[6];
    const float* bk = (const float*)d_in[7];
    const float* Wv = (const float*)d_in[8];
    const float* bv = (const float*)d_in[9];
    const float* Wp = (const float*)d_in[10];
    const float* ub = (const float*)d_in[11];
    const float* vbias = (const float*)d_in[12];
    const float* Wo = (const float*)d_in[13];
    const float* bo = (const float*)d_in[14];
    float* out = (float*)d_out;
    ushort_t* ws = (ushort_t*)d_ws;

    ushort_t* wT  = ws;                       // 5 x 262144
    ushort_t* Qu  = ws + 1310720;
    ushort_t* Qv  = Qu + 4194304;
    ushort_t* Kp  = Qv + 4194304;
    ushort_t* Pp  = Kp + 4194304;
    ushort_t* Vt  = Pp + 4194304;
    ushort_t* ctx = Vt + 4194304;

    prep_kernel<<<dim3(8, 8, 5), 256, 0, stream>>>(Wq, Wk, Wv, Wp, Wo, wT);
    proj_gemm<<<dim3(4, 64, 4), 256, 0, stream>>>(q, k, v, pe, wT, bq, bk, bv,
                                                  ub, vbias, Qu, Qv, Kp, Pp, Vt);
    attn_kernel<<<2048, 256, 0, stream>>>(Qu, Qv, Kp, Pp, Vt, ctx);
    out_gemm<<<dim3(4, 64), 256, 0, stream>>>(ctx, wT + 4 * 262144, bo, out);
}